// Round 14
// baseline (46.104 us; speedup 1.0000x reference)
//
#include <hip/hip_runtime.h>
#include <math.h>

#define NPARTS 64
#define CELL 28
#define CDIM 2048
#define BDIM 256
#define SPLIT 8
#define CH_PER_BLOCK (CDIM / SPLIT)     // 256 channels per slice
#define DIS_BLOCKS (BDIM * SPLIT)       // 2048 blocks for dis phase

// ---- d_ws layout (float offsets) ----
#define WS_SAME   0                                     // 16384
#define WS_PART   (WS_SAME + BDIM * NPARTS)             // 2048*192 = 393216
#define WS_MBT    (WS_PART + DIS_BLOCKS * 3 * NPARTS)   // f16 tables (negated)
#define WS_MMT    (WS_MBT + CDIM * NPARTS / 2)          // each = 65536 floats
#define WS_MNT    (WS_MMT + CDIM * NPARTS / 2)
#define WS_CELL   (WS_MNT + CDIM * NPARTS / 2)          // int cells, 16384
#define WS_DIMG   (WS_CELL + BDIM * NPARTS)             // 256*2 doubles (even offset)
#define WS_TICK   (WS_DIMG + 4 * BDIM)                  // 256 uint tickets

// k_prep geometry: 384 transpose blocks + 64 cell blocks
#define TR_BLOCKS   384
#define PREP_BLOCKS (TR_BLOCKS + 64)    // 448

typedef _Float16 h2_t __attribute__((ext_vector_type(2)));

static __device__ __forceinline__ h2_t bperm_h2(int baddr, h2_t v) {
    int r = __builtin_amdgcn_ds_bpermute(baddr, __builtin_bit_cast(int, v));
    return __builtin_bit_cast(h2_t, r);
}

static __device__ __forceinline__ h2_t pack_h2(float a, float b) {
    return __builtin_bit_cast(h2_t, __builtin_amdgcn_cvt_pkrtz(a, b));
}

// ---------------------------------------------------------------------------
// Prep kernel (pure; unblocks k_dis2 fast).
// Blocks [0,384): mean transpose, lane = part (coalesced uint2 writes).
// Blocks [384,448): cell precompute. Block 0 also resets tickets.
// ---------------------------------------------------------------------------
__global__ __launch_bounds__(256) void k_prep(
    const float* __restrict__ mb, const float* __restrict__ mm,
    const float* __restrict__ mn, const int* __restrict__ cx,
    const int* __restrict__ cy, float* __restrict__ ws)
{
    const int g = blockIdx.x;
    const int t = threadIdx.x;

    if (g < TR_BLOCKS) {
        if (g == 0) ((unsigned*)ws)[WS_TICK + t] = 0u;   // reset 256 tickets
        const int tid  = g * 256 + t;        // 0..98303
        const int kind = tid >> 15;          // 32768 threads per kind
        const int idx  = tid & 32767;
        const int cq   = idx >> 6;           // channel quad 0..511
        const int p    = idx & 63;           // part = lane
        const float* src = (kind == 0) ? mb : (kind == 1) ? mm : mn;
        const float4 s4 = *(const float4*)(src + (size_t)p * CDIM + cq * 4);
        uint2 v;
        v.x = __builtin_bit_cast(unsigned, pack_h2(-s4.x, -s4.y));
        v.y = __builtin_bit_cast(unsigned, pack_h2(-s4.z, -s4.w));
        _Float16* dst = (_Float16*)(ws + ((kind == 0) ? WS_MBT :
                                          (kind == 1) ? WS_MMT : WS_MNT));
        *(uint2*)(dst + ((cq << 8) + (p << 2))) = v;
        return;
    }

    const int t2 = (g - TR_BLOCKS) * 256 + t;   // < BDIM*NPARTS, = p*256+b
    const int b = t2 & (BDIM - 1);
    const int p = t2 >> 8;
    const int x = cx[t2] / CELL;
    const int y = cy[t2] / CELL;
    ((int*)ws)[WS_CELL + b * NPARTS + p] = x * 8 + y;
}

// ---------------------------------------------------------------------------
// Dis kernel, f16-packed math + fused per-image combine (same-XCD ticket).
// Block g: slice s = g>>8, image b = g&255 => g % 8 == b % 8: all 8 slice
// blocks of an image land on ONE XCD, partials coherent in that L2.
// fm loads are NONTEMPORAL: each line is consumed exactly once device-wide,
// so keep the stream from evicting the L2-resident mean tables.
// ---------------------------------------------------------------------------
__global__ __launch_bounds__(256) void k_dis2(
    const float* __restrict__ fm,
    const int* __restrict__ labels,
    float* __restrict__ ws)
{
    const int g = blockIdx.x;
    const int s = g >> 8, b = g & (BDIM - 1);
    const int t = threadIdx.x;
    const int lane = t & 63, w = t >> 6;

    const int cell  = ((const int*)ws)[WS_CELL + b * NPARTS + lane];
    const int baddr = cell << 2;           // byte address for bpermute

    const int c0 = s * CH_PER_BLOCK + w * 64;     // this wave's first channel
    const float* fmb = fm + (size_t)b * (CDIM * 64) + (size_t)c0 * 64;
    const uint2* mbt = (const uint2*)(ws + WS_MBT) + ((c0 >> 2) << 6) + lane;
    const uint2* mmt = (const uint2*)(ws + WS_MMT) + ((c0 >> 2) << 6) + lane;
    const uint2* mnt = (const uint2*)(ws + WS_MNT) + ((c0 >> 2) << 6) + lane;

    h2_t A00 = {0, 0}, A01 = {0, 0};   // mean b, pair slots (c0c1 / c2c3)
    h2_t A10 = {0, 0}, A11 = {0, 0};   // mean m
    h2_t A20 = {0, 0}, A21 = {0, 0};   // mean n

    #pragma unroll 4
    for (int k = 0; k < 16; ++k) {          // 4 channels per iter
        const float* r = fmb + k * 256;
        float v0 = __builtin_nontemporal_load(r + lane);
        float v1 = __builtin_nontemporal_load(r + 64 + lane);
        float v2 = __builtin_nontemporal_load(r + 128 + lane);
        float v3 = __builtin_nontemporal_load(r + 192 + lane);
        uint2 nmb = mbt[k * 64];
        uint2 nmm = mmt[k * 64];
        uint2 nmn = mnt[k * 64];

        h2_t p01 = pack_h2(v0, v1);
        h2_t p23 = pack_h2(v2, v3);
        h2_t u01 = bperm_h2(baddr, p01);
        h2_t u23 = bperm_h2(baddr, p23);

        h2_t d;
        d = u01 + __builtin_bit_cast(h2_t, nmb.x); A00 += d * d;
        d = u23 + __builtin_bit_cast(h2_t, nmb.y); A01 += d * d;
        d = u01 + __builtin_bit_cast(h2_t, nmm.x); A10 += d * d;
        d = u23 + __builtin_bit_cast(h2_t, nmm.y); A11 += d * d;
        d = u01 + __builtin_bit_cast(h2_t, nmn.x); A20 += d * d;
        d = u23 + __builtin_bit_cast(h2_t, nmn.y); A21 += d * d;
    }

    float a0 = (float)A00.x + (float)A00.y + (float)A01.x + (float)A01.y;
    float a1 = (float)A10.x + (float)A10.y + (float)A11.x + (float)A11.y;
    float a2 = (float)A20.x + (float)A20.y + (float)A21.x + (float)A21.y;

    __shared__ float red[4][3][64];
    red[w][0][lane] = a0; red[w][1][lane] = a1; red[w][2][lane] = a2;
    __syncthreads();
    if (t < 64) {
        float s0 = red[0][0][t] + red[1][0][t] + red[2][0][t] + red[3][0][t];
        float s1 = red[0][1][t] + red[1][1][t] + red[2][1][t] + red[3][1][t];
        float s2 = red[0][2][t] + red[1][2][t] + red[2][2][t] + red[3][2][t];
        float* po = ws + WS_PART + (size_t)(b * SPLIT + s) * 192;
        po[t] = s0; po[64 + t] = s1; po[128 + t] = s2;
    }

    // ---- per-image ticket (no fence; partials stay in this XCD's L2) ----
    asm volatile("s_waitcnt vmcnt(0)" ::: "memory");
    __shared__ unsigned flag;
    if (t == 0) flag = atomicAdd(&((unsigned*)ws)[WS_TICK + b], 1u);
    __syncthreads();
    if (flag != SPLIT - 1) return;

    // ---- image epilogue (8th arriver; same XCD as all 8 writers) ----
    __shared__ float sm2[3][64];
    const float* pp = ws + WS_PART + (size_t)(b * SPLIT) * 192;
    if (t < 192) {
        const int j = t >> 6, p = t & 63;
        float acc = 0.f;
        #pragma unroll
        for (int sl = 0; sl < SPLIT; ++sl)
            acc += __hip_atomic_load(pp + sl * 192 + j * 64 + p,
                                     __ATOMIC_RELAXED, __HIP_MEMORY_SCOPE_AGENT);
        sm2[j][p] = acc;
    }
    __syncthreads();

    if (t < 64) {
        float db = sqrtf(sm2[0][t]);
        float dm = sqrtf(sm2[1][t]);
        float dn = sqrtf(sm2[2][t]);
        const int lab = labels[b];
        float same_v = (lab == 0) ? db : ((lab == 1) ? dm : dn);
        ws[WS_SAME + b * NPARTS + t] = same_v;      // plain store: kernel-end flush
        double ds = (double)same_v;
        double d3 = (double)(db + dm + dn);
        for (int off = 32; off; off >>= 1) {
            ds += __shfl_down(ds, off);
            d3 += __shfl_down(d3, off);
        }
        if (t == 0) {
            double* dimg = (double*)(ws + WS_DIMG);
            dimg[2 * b]     = ds;
            dimg[2 * b + 1] = d3;
        }
    }
}

// ---------------------------------------------------------------------------
// Tail kernel: block 0 = deterministic loss (float4 hinge reads); blocks
// 1..256 = distances_im + val for image g-1 (runs concurrently with loss).
// ---------------------------------------------------------------------------
__global__ __launch_bounds__(256) void k_tail(
    const float* __restrict__ emb,
    const float* __restrict__ meb, const float* __restrict__ mem_,
    const float* __restrict__ men,
    const float* __restrict__ ws, float* __restrict__ out)
{
    const int g = blockIdx.x;
    const int t = threadIdx.x;

    if (g == 0) {
        // ---- final loss (reads k_dis2's same[] + dimg, stream-ordered) ----
        const int N = BDIM * NPARTS;
        const float4* same4 = (const float4*)(ws + WS_SAME);
        const double* dimg = (const double*)(ws + WS_DIMG);

        double ss = dimg[2 * t];        // t spans 0..255 = all images
        double s3 = dimg[2 * t + 1];

        __shared__ double r1[256], r2[256];
        r1[t] = s3; r2[t] = ss;
        __syncthreads();
        for (int off = 128; off; off >>= 1) {
            if (t < off) { r1[t] += r1[t + off]; r2[t] += r2[t + off]; }
            __syncthreads();
        }
        __shared__ float dmS;
        if (t == 0) dmS = (float)((r1[0] - r2[0]) / (double)(BDIM * 2 * NPARTS));
        __syncthreads();
        const float dmean = dmS;

        double sl = 0.0;
        #pragma unroll 4
        for (int i = t; i < N / 4; i += 256) {
            float4 sv = same4[i];
            float v0 = 1.0f + sv.x - dmean;
            float v1 = 1.0f + sv.y - dmean;
            float v2 = 1.0f + sv.z - dmean;
            float v3 = 1.0f + sv.w - dmean;
            sl += (v0 > 0.f) ? (double)v0 : 0.0;
            sl += (v1 > 0.f) ? (double)v1 : 0.0;
            sl += (v2 > 0.f) ? (double)v2 : 0.0;
            sl += (v3 > 0.f) ? (double)v3 : 0.0;
        }
        r1[t] = sl;
        __syncthreads();
        for (int off = 128; off; off >>= 1) {
            if (t < off) r1[t] += r1[t + off];
            __syncthreads();
        }
        if (t == 0) out[3 * BDIM + BDIM] = (float)(r1[0] / (double)N);
        return;
    }

    // ---- distances_im + val (exact fp32 path), image b = g-1 ----
    const int b = g - 1;
    const float* e = emb + (size_t)b * CDIM;

    float sb = 0.f, sm = 0.f, sn = 0.f;
    for (int c = t; c < CDIM; c += 256) {
        float v = e[c];
        float d0 = v - meb[c];  sb += d0 * d0;
        float d1 = v - mem_[c]; sm += d1 * d1;
        float d2 = v - men[c];  sn += d2 * d2;
    }
    for (int off = 32; off; off >>= 1) {
        sb += __shfl_down(sb, off);
        sm += __shfl_down(sm, off);
        sn += __shfl_down(sn, off);
    }
    __shared__ float red[3][4];
    const int wave = t >> 6;
    if ((t & 63) == 0) { red[0][wave] = sb; red[1][wave] = sm; red[2][wave] = sn; }
    __syncthreads();
    if (t == 0) {
        float tb = red[0][0] + red[0][1] + red[0][2] + red[0][3];
        float tm = red[1][0] + red[1][1] + red[1][2] + red[1][3];
        float tn = red[2][0] + red[2][1] + red[2][2] + red[2][3];
        float db = sqrtf(tb), dm = sqrtf(tm), dn = sqrtf(tn);
        out[b * 3 + 0] = db;
        out[b * 3 + 1] = dm;
        out[b * 3 + 2] = dn;
        int idx = 0; float best = db;
        if (dm < best) { best = dm; idx = 1; }
        if (dn < best) { idx = 2; }
        out[3 * BDIM + b] = (float)idx;
    }
}

extern "C" void kernel_launch(void* const* d_in, const int* in_sizes, int n_in,
                              void* d_out, int out_size, void* d_ws, size_t ws_size,
                              hipStream_t stream)
{
    const int*   labels = (const int*)  d_in[0];
    const float* emb    = (const float*)d_in[1];
    const float* fm     = (const float*)d_in[2];
    const float* mb     = (const float*)d_in[3];
    const float* mm     = (const float*)d_in[4];
    const float* mn     = (const float*)d_in[5];
    const int*   cx     = (const int*)  d_in[6];
    const int*   cy     = (const int*)  d_in[7];
    const float* meb    = (const float*)d_in[8];
    const float* mem_   = (const float*)d_in[9];
    const float* men    = (const float*)d_in[10];

    float* out = (float*)d_out;
    float* ws  = (float*)d_ws;

    k_prep<<<PREP_BLOCKS, 256, 0, stream>>>(mb, mm, mn, cx, cy, ws);
    k_dis2<<<DIS_BLOCKS, 256, 0, stream>>>(fm, labels, ws);
    k_tail<<<1 + BDIM, 256, 0, stream>>>(emb, meb, mem_, men, ws, out);
}

// Round 15
// 39.040 us; speedup vs baseline: 1.1809x; 1.1809x over previous
//
#include <hip/hip_runtime.h>
#include <math.h>

#define NPARTS 64
#define CELL 28
#define CDIM 2048
#define BDIM 256
#define SPLIT 8
#define CH_PER_BLOCK (CDIM / SPLIT)     // 256 channels per slice
#define DIS_BLOCKS (BDIM * SPLIT)       // 2048 blocks for dis phase

// ---- d_ws layout (float offsets) ----
#define WS_SAME   0                                     // 16384
#define WS_PART   (WS_SAME + BDIM * NPARTS)             // 2048*192 = 393216
#define WS_MBT    (WS_PART + DIS_BLOCKS * 3 * NPARTS)   // f16 tables (negated)
#define WS_MMT    (WS_MBT + CDIM * NPARTS / 2)          // each = 65536 floats
#define WS_MNT    (WS_MMT + CDIM * NPARTS / 2)
#define WS_CELL   (WS_MNT + CDIM * NPARTS / 2)          // int cells, 16384
#define WS_DIMG   (WS_CELL + BDIM * NPARTS)             // 256*2 doubles (even offset)
#define WS_TICK   (WS_DIMG + 4 * BDIM)                  // 256 uint tickets

// k_prep geometry: 384 transpose blocks + 64 cell blocks
#define TR_BLOCKS   384
#define PREP_BLOCKS (TR_BLOCKS + 64)    // 448

typedef _Float16 h2_t __attribute__((ext_vector_type(2)));

static __device__ __forceinline__ h2_t bperm_h2(int baddr, h2_t v) {
    int r = __builtin_amdgcn_ds_bpermute(baddr, __builtin_bit_cast(int, v));
    return __builtin_bit_cast(h2_t, r);
}

static __device__ __forceinline__ h2_t pack_h2(float a, float b) {
    return __builtin_bit_cast(h2_t, __builtin_amdgcn_cvt_pkrtz(a, b));
}

// ---------------------------------------------------------------------------
// Prep kernel (pure; unblocks k_dis2 fast).
// Blocks [0,384): mean transpose, lane = part (coalesced uint2 writes).
// Blocks [384,448): cell precompute. Block 0 also resets tickets.
// ---------------------------------------------------------------------------
__global__ __launch_bounds__(256) void k_prep(
    const float* __restrict__ mb, const float* __restrict__ mm,
    const float* __restrict__ mn, const int* __restrict__ cx,
    const int* __restrict__ cy, float* __restrict__ ws)
{
    const int g = blockIdx.x;
    const int t = threadIdx.x;

    if (g < TR_BLOCKS) {
        if (g == 0) ((unsigned*)ws)[WS_TICK + t] = 0u;   // reset 256 tickets
        const int tid  = g * 256 + t;        // 0..98303
        const int kind = tid >> 15;          // 32768 threads per kind
        const int idx  = tid & 32767;
        const int cq   = idx >> 6;           // channel quad 0..511
        const int p    = idx & 63;           // part = lane
        const float* src = (kind == 0) ? mb : (kind == 1) ? mm : mn;
        const float4 s4 = *(const float4*)(src + (size_t)p * CDIM + cq * 4);
        uint2 v;
        v.x = __builtin_bit_cast(unsigned, pack_h2(-s4.x, -s4.y));
        v.y = __builtin_bit_cast(unsigned, pack_h2(-s4.z, -s4.w));
        _Float16* dst = (_Float16*)(ws + ((kind == 0) ? WS_MBT :
                                          (kind == 1) ? WS_MMT : WS_MNT));
        *(uint2*)(dst + ((cq << 8) + (p << 2))) = v;
        return;
    }

    const int t2 = (g - TR_BLOCKS) * 256 + t;   // < BDIM*NPARTS, = p*256+b
    const int b = t2 & (BDIM - 1);
    const int p = t2 >> 8;
    const int x = cx[t2] / CELL;
    const int y = cy[t2] / CELL;
    ((int*)ws)[WS_CELL + b * NPARTS + p] = x * 8 + y;
}

// ---------------------------------------------------------------------------
// Dis kernel, f16-packed math + fused per-image combine (same-XCD ticket).
// Block g: slice s = g>>8, image b = g&255 => g % 8 == b % 8: all 8 slice
// blocks of an image land on ONE XCD, partials coherent in that L2.
// PLAIN fm loads (R14 measured: nontemporal costs ~4 us on this stream).
// ---------------------------------------------------------------------------
__global__ __launch_bounds__(256) void k_dis2(
    const float* __restrict__ fm,
    const int* __restrict__ labels,
    float* __restrict__ ws)
{
    const int g = blockIdx.x;
    const int s = g >> 8, b = g & (BDIM - 1);
    const int t = threadIdx.x;
    const int lane = t & 63, w = t >> 6;

    const int cell  = ((const int*)ws)[WS_CELL + b * NPARTS + lane];
    const int baddr = cell << 2;           // byte address for bpermute

    const int c0 = s * CH_PER_BLOCK + w * 64;     // this wave's first channel
    const float* fmb = fm + (size_t)b * (CDIM * 64) + (size_t)c0 * 64;
    const uint2* mbt = (const uint2*)(ws + WS_MBT) + ((c0 >> 2) << 6) + lane;
    const uint2* mmt = (const uint2*)(ws + WS_MMT) + ((c0 >> 2) << 6) + lane;
    const uint2* mnt = (const uint2*)(ws + WS_MNT) + ((c0 >> 2) << 6) + lane;

    h2_t A00 = {0, 0}, A01 = {0, 0};   // mean b, pair slots (c0c1 / c2c3)
    h2_t A10 = {0, 0}, A11 = {0, 0};   // mean m
    h2_t A20 = {0, 0}, A21 = {0, 0};   // mean n

    #pragma unroll 4
    for (int k = 0; k < 16; ++k) {          // 4 channels per iter
        const float* r = fmb + k * 256;
        float v0 = r[lane];
        float v1 = r[64 + lane];
        float v2 = r[128 + lane];
        float v3 = r[192 + lane];
        uint2 nmb = mbt[k * 64];
        uint2 nmm = mmt[k * 64];
        uint2 nmn = mnt[k * 64];

        h2_t p01 = pack_h2(v0, v1);
        h2_t p23 = pack_h2(v2, v3);
        h2_t u01 = bperm_h2(baddr, p01);
        h2_t u23 = bperm_h2(baddr, p23);

        h2_t d;
        d = u01 + __builtin_bit_cast(h2_t, nmb.x); A00 += d * d;
        d = u23 + __builtin_bit_cast(h2_t, nmb.y); A01 += d * d;
        d = u01 + __builtin_bit_cast(h2_t, nmm.x); A10 += d * d;
        d = u23 + __builtin_bit_cast(h2_t, nmm.y); A11 += d * d;
        d = u01 + __builtin_bit_cast(h2_t, nmn.x); A20 += d * d;
        d = u23 + __builtin_bit_cast(h2_t, nmn.y); A21 += d * d;
    }

    float a0 = (float)A00.x + (float)A00.y + (float)A01.x + (float)A01.y;
    float a1 = (float)A10.x + (float)A10.y + (float)A11.x + (float)A11.y;
    float a2 = (float)A20.x + (float)A20.y + (float)A21.x + (float)A21.y;

    __shared__ float red[4][3][64];
    red[w][0][lane] = a0; red[w][1][lane] = a1; red[w][2][lane] = a2;
    __syncthreads();
    if (t < 64) {
        float s0 = red[0][0][t] + red[1][0][t] + red[2][0][t] + red[3][0][t];
        float s1 = red[0][1][t] + red[1][1][t] + red[2][1][t] + red[3][1][t];
        float s2 = red[0][2][t] + red[1][2][t] + red[2][2][t] + red[3][2][t];
        float* po = ws + WS_PART + (size_t)(b * SPLIT + s) * 192;
        po[t] = s0; po[64 + t] = s1; po[128 + t] = s2;
    }

    // ---- per-image ticket (no fence; partials stay in this XCD's L2) ----
    asm volatile("s_waitcnt vmcnt(0)" ::: "memory");
    __shared__ unsigned flag;
    if (t == 0) flag = atomicAdd(&((unsigned*)ws)[WS_TICK + b], 1u);
    __syncthreads();
    if (flag != SPLIT - 1) return;

    // ---- image epilogue (8th arriver; same XCD as all 8 writers) ----
    __shared__ float sm2[3][64];
    const float* pp = ws + WS_PART + (size_t)(b * SPLIT) * 192;
    if (t < 192) {
        const int j = t >> 6, p = t & 63;
        float acc = 0.f;
        #pragma unroll
        for (int sl = 0; sl < SPLIT; ++sl)
            acc += __hip_atomic_load(pp + sl * 192 + j * 64 + p,
                                     __ATOMIC_RELAXED, __HIP_MEMORY_SCOPE_AGENT);
        sm2[j][p] = acc;
    }
    __syncthreads();

    if (t < 64) {
        float db = sqrtf(sm2[0][t]);
        float dm = sqrtf(sm2[1][t]);
        float dn = sqrtf(sm2[2][t]);
        const int lab = labels[b];
        float same_v = (lab == 0) ? db : ((lab == 1) ? dm : dn);
        ws[WS_SAME + b * NPARTS + t] = same_v;      // plain store: kernel-end flush
        double ds = (double)same_v;
        double d3 = (double)(db + dm + dn);
        for (int off = 32; off; off >>= 1) {
            ds += __shfl_down(ds, off);
            d3 += __shfl_down(d3, off);
        }
        if (t == 0) {
            double* dimg = (double*)(ws + WS_DIMG);
            dimg[2 * b]     = ds;
            dimg[2 * b + 1] = d3;
        }
    }
}

// ---------------------------------------------------------------------------
// Tail kernel: block 0 = deterministic loss (float4 hinge reads); blocks
// 1..256 = distances_im + val for image g-1 (runs concurrently with loss).
// ---------------------------------------------------------------------------
__global__ __launch_bounds__(256) void k_tail(
    const float* __restrict__ emb,
    const float* __restrict__ meb, const float* __restrict__ mem_,
    const float* __restrict__ men,
    const float* __restrict__ ws, float* __restrict__ out)
{
    const int g = blockIdx.x;
    const int t = threadIdx.x;

    if (g == 0) {
        // ---- final loss (reads k_dis2's same[] + dimg, stream-ordered) ----
        const int N = BDIM * NPARTS;
        const float4* same4 = (const float4*)(ws + WS_SAME);
        const double* dimg = (const double*)(ws + WS_DIMG);

        double ss = dimg[2 * t];        // t spans 0..255 = all images
        double s3 = dimg[2 * t + 1];

        __shared__ double r1[256], r2[256];
        r1[t] = s3; r2[t] = ss;
        __syncthreads();
        for (int off = 128; off; off >>= 1) {
            if (t < off) { r1[t] += r1[t + off]; r2[t] += r2[t + off]; }
            __syncthreads();
        }
        __shared__ float dmS;
        if (t == 0) dmS = (float)((r1[0] - r2[0]) / (double)(BDIM * 2 * NPARTS));
        __syncthreads();
        const float dmean = dmS;

        double sl = 0.0;
        #pragma unroll 4
        for (int i = t; i < N / 4; i += 256) {
            float4 sv = same4[i];
            float v0 = 1.0f + sv.x - dmean;
            float v1 = 1.0f + sv.y - dmean;
            float v2 = 1.0f + sv.z - dmean;
            float v3 = 1.0f + sv.w - dmean;
            sl += (v0 > 0.f) ? (double)v0 : 0.0;
            sl += (v1 > 0.f) ? (double)v1 : 0.0;
            sl += (v2 > 0.f) ? (double)v2 : 0.0;
            sl += (v3 > 0.f) ? (double)v3 : 0.0;
        }
        r1[t] = sl;
        __syncthreads();
        for (int off = 128; off; off >>= 1) {
            if (t < off) r1[t] += r1[t + off];
            __syncthreads();
        }
        if (t == 0) out[3 * BDIM + BDIM] = (float)(r1[0] / (double)N);
        return;
    }

    // ---- distances_im + val (exact fp32 path), image b = g-1 ----
    const int b = g - 1;
    const float* e = emb + (size_t)b * CDIM;

    float sb = 0.f, sm = 0.f, sn = 0.f;
    for (int c = t; c < CDIM; c += 256) {
        float v = e[c];
        float d0 = v - meb[c];  sb += d0 * d0;
        float d1 = v - mem_[c]; sm += d1 * d1;
        float d2 = v - men[c];  sn += d2 * d2;
    }
    for (int off = 32; off; off >>= 1) {
        sb += __shfl_down(sb, off);
        sm += __shfl_down(sm, off);
        sn += __shfl_down(sn, off);
    }
    __shared__ float red[3][4];
    const int wave = t >> 6;
    if ((t & 63) == 0) { red[0][wave] = sb; red[1][wave] = sm; red[2][wave] = sn; }
    __syncthreads();
    if (t == 0) {
        float tb = red[0][0] + red[0][1] + red[0][2] + red[0][3];
        float tm = red[1][0] + red[1][1] + red[1][2] + red[1][3];
        float tn = red[2][0] + red[2][1] + red[2][2] + red[2][3];
        float db = sqrtf(tb), dm = sqrtf(tm), dn = sqrtf(tn);
        out[b * 3 + 0] = db;
        out[b * 3 + 1] = dm;
        out[b * 3 + 2] = dn;
        int idx = 0; float best = db;
        if (dm < best) { best = dm; idx = 1; }
        if (dn < best) { idx = 2; }
        out[3 * BDIM + b] = (float)idx;
    }
}

extern "C" void kernel_launch(void* const* d_in, const int* in_sizes, int n_in,
                              void* d_out, int out_size, void* d_ws, size_t ws_size,
                              hipStream_t stream)
{
    const int*   labels = (const int*)  d_in[0];
    const float* emb    = (const float*)d_in[1];
    const float* fm     = (const float*)d_in[2];
    const float* mb     = (const float*)d_in[3];
    const float* mm     = (const float*)d_in[4];
    const float* mn     = (const float*)d_in[5];
    const int*   cx     = (const int*)  d_in[6];
    const int*   cy     = (const int*)  d_in[7];
    const float* meb    = (const float*)d_in[8];
    const float* mem_   = (const float*)d_in[9];
    const float* men    = (const float*)d_in[10];

    float* out = (float*)d_out;
    float* ws  = (float*)d_ws;

    k_prep<<<PREP_BLOCKS, 256, 0, stream>>>(mb, mm, mn, cx, cy, ws);
    k_dis2<<<DIS_BLOCKS, 256, 0, stream>>>(fm, labels, ws);
    k_tail<<<1 + BDIM, 256, 0, stream>>>(emb, meb, mem_, men, ws, out);
}